// Round 2
// baseline (320.384 us; speedup 1.0000x reference)
//
#include <hip/hip_runtime.h>

typedef __bf16 bf16_t;
typedef bf16_t bf16x8 __attribute__((ext_vector_type(8)));
typedef float f32x4 __attribute__((ext_vector_type(4)));

#define NSEQ 2048
#define EMB 512
#define HEADS 8
#define HD 64
#define BATCH 4
#define LOG2E 1.4426950408889634f

// ---------------------------------------------------------------------------
// fp32 -> bf16 pre-convert: x (4M el), Wk (256K), Wv (256K). Memory-bound ~5us.
// ---------------------------------------------------------------------------
#define CX (BATCH * NSEQ * EMB / 8)
#define CW (EMB * EMB / 8)
__global__ __launch_bounds__(256) void convert_kernel(
    const float* __restrict__ x, const float* __restrict__ Wk,
    const float* __restrict__ Wv,
    bf16_t* __restrict__ xb, bf16_t* __restrict__ Wkb, bf16_t* __restrict__ Wvb)
{
  const int total = CX + 2 * CW;
  for (int c = blockIdx.x * 256 + threadIdx.x; c < total; c += gridDim.x * 256) {
    const float* src;
    bf16_t* dst;
    int off;
    if (c < CX)            { src = x;  dst = xb;  off = c; }
    else if (c < CX + CW)  { src = Wk; dst = Wkb; off = c - CX; }
    else                   { src = Wv; dst = Wvb; off = c - CX - CW; }
    const float4 a = *(const float4*)(src + (size_t)off * 8);
    const float4 bq = *(const float4*)(src + (size_t)off * 8 + 4);
    bf16x8 v;
    v[0] = (bf16_t)a.x;  v[1] = (bf16_t)a.y;  v[2] = (bf16_t)a.z;  v[3] = (bf16_t)a.w;
    v[4] = (bf16_t)bq.x; v[5] = (bf16_t)bq.y; v[6] = (bf16_t)bq.z; v[7] = (bf16_t)bq.w;
    *(bf16x8*)(dst + (size_t)off * 8) = v;
  }
}

// ---------------------------------------------------------------------------
// Projection GEMM (bf16 in, bf16 out): C[8192,512] = xb @ Wb^T + bias.
//   z==0: Kh[b][h][n][d]   z==1: Vt[b][h][d][n]
// 128x128 tile, BK=32, 4 waves (2x2 of 64x64). Epilogue transposes through
// LDS so both output layouts get coalesced bf16x8 stores.
// ---------------------------------------------------------------------------
__global__ __launch_bounds__(256) void proj_kernel(
    const bf16_t* __restrict__ xb,
    const bf16_t* __restrict__ Wkb, const float* __restrict__ bk,
    const bf16_t* __restrict__ Wvb, const float* __restrict__ bv,
    bf16_t* __restrict__ Kh, bf16_t* __restrict__ Vt)
{
  const int zz = blockIdx.z;
  const bf16_t* __restrict__ W    = zz ? Wvb : Wkb;
  const float*  __restrict__ bias = zz ? bv : bk;

  __shared__ union {
    struct {
      __align__(16) bf16_t Al[128][40];  // pitch 40 -> conflict-free frag reads
      __align__(16) bf16_t Bl[128][40];
    } s;
    __align__(16) bf16_t T[128][136];    // epilogue transpose buffer
  } u;

  const int t    = threadIdx.x;
  const int w    = t >> 6;
  const int lane = t & 63;
  const int quad = lane >> 4;
  const int l15  = lane & 15;
  const int wr   = w >> 1, wc = w & 1;
  const int m0   = blockIdx.x * 128;
  const int n0   = blockIdx.y * 128;

  f32x4 acc[4][4] = {};

  for (int k0 = 0; k0 < EMB; k0 += 32) {
#pragma unroll
    for (int i = 0; i < 2; ++i) {
      const int idx  = t + i * 256;        // 0..511
      const int row  = idx >> 2;           // 0..127
      const int col8 = (idx & 3) * 8;      // 0,8,16,24
      *(bf16x8*)(&u.s.Al[row][col8]) =
          *(const bf16x8*)(xb + (size_t)(m0 + row) * EMB + k0 + col8);
      *(bf16x8*)(&u.s.Bl[row][col8]) =
          *(const bf16x8*)(W + (size_t)(n0 + row) * EMB + k0 + col8);
    }
    __syncthreads();

    bf16x8 af[4], bfr[4];
#pragma unroll
    for (int mt = 0; mt < 4; ++mt)
      af[mt] = *(const bf16x8*)(&u.s.Al[wr * 64 + mt * 16 + l15][quad * 8]);
#pragma unroll
    for (int nt = 0; nt < 4; ++nt)
      bfr[nt] = *(const bf16x8*)(&u.s.Bl[wc * 64 + nt * 16 + l15][quad * 8]);
#pragma unroll
    for (int mt = 0; mt < 4; ++mt)
#pragma unroll
      for (int nt = 0; nt < 4; ++nt)
        acc[mt][nt] = __builtin_amdgcn_mfma_f32_16x16x32_bf16(
            af[mt], bfr[nt], acc[mt][nt], 0, 0, 0);
    __syncthreads();
  }

  // Epilogue stage 1: +bias, bf16, into LDS in OUTPUT-major layout.
#pragma unroll
  for (int mt = 0; mt < 4; ++mt) {
#pragma unroll
    for (int nt = 0; nt < 4; ++nt) {
      const int F  = wc * 64 + nt * 16 + l15;   // local feature 0..127
      const float bb = bias[n0 + F];
#pragma unroll
      for (int reg = 0; reg < 4; ++reg) {
        const int R = wr * 64 + mt * 16 + quad * 4 + reg;  // local row 0..127
        const float v = acc[mt][nt][reg] + bb;
        if (!zz) u.T[R][F] = (bf16_t)v;   // Kh: row-major [n][feat]
        else     u.T[F][R] = (bf16_t)v;   // Vt: [feat][n]
      }
    }
  }
  __syncthreads();

  // Epilogue stage 2: coalesced bf16x8 stores.
#pragma unroll
  for (int i = 0; i < 8; ++i) {
    const int q  = t + i * 256;       // 0..2047
    const int R  = q >> 4;            // LDS row 0..127
    const int C8 = (q & 15) * 8;      // LDS col chunk
    const bf16x8 v = *(const bf16x8*)(&u.T[R][C8]);
    if (!zz) {
      const int gr = m0 + R, b = gr >> 11, n = gr & (NSEQ - 1);
      const int c = n0 + C8, hh = c >> 6, d = c & 63;
      *(bf16x8*)(Kh + (((size_t)(b * HEADS + hh)) * NSEQ + n) * HD + d) = v;
    } else {
      const int c = n0 + R, hh = c >> 6, d = c & 63;
      const int gr = m0 + C8, b = gr >> 11, n = gr & (NSEQ - 1);
      *(bf16x8*)(Vt + (((size_t)(b * HEADS + hh)) * HD + d) * NSEQ + n) = v;
    }
  }
}

// ---------------------------------------------------------------------------
// Flash attention, Q = K, FIXED row max m_i = ||k_i||^2 (diagonal dominates
// by Cauchy-Schwarz within fp32 range). No running max, no rescale, no
// per-tile cross-lane reductions: l accumulated per-lane, reduced once.
// 1 wave = 16 Q rows; block = 64 rows; grid (bh=32, mtile=32) -> 1024 blocks,
// 16 waves/CU. id%8 XCD mapping gives each XCD 4 heads (2MB K/V, fits L2).
// ---------------------------------------------------------------------------
__global__ __launch_bounds__(256, 4) void flash_kernel(
    const bf16_t* __restrict__ Kh, const bf16_t* __restrict__ Vt,
    float* __restrict__ out)
{
  // pitch 68: 4-row quad stride = 544B = 8 banks -> scatter writes conflict-free
  __shared__ __align__(16) bf16_t Pl[4][16][68];

  const int t    = threadIdx.x;
  const int w    = t >> 6;
  const int lane = t & 63;
  const int quad = lane >> 4;
  const int l15  = lane & 15;

  const int bh = blockIdx.x;           // 0..31  (id%8 == bh%8 -> XCD locality)
  const int b  = bh >> 3, h = bh & 7;
  const int rowbase = blockIdx.y * 64 + w * 16;

  const bf16_t* __restrict__ Kb = Kh + (size_t)bh * NSEQ * HD;
  const bf16_t* __restrict__ Vb = Vt + (size_t)bh * HD * NSEQ;

  // Q fragments (A-layout), resident whole kernel
  bf16x8 qf[2];
#pragma unroll
  for (int kk = 0; kk < 2; ++kk)
    qf[kk] = *(const bf16x8*)(Kb + (size_t)(rowbase + l15) * HD + kk * 32 + quad * 8);

  // m_i = ||k_i||^2 from the resident Q frags; 2 shuffles to reduce over quads.
  float ss = 0.f;
#pragma unroll
  for (int kk = 0; kk < 2; ++kk)
#pragma unroll
    for (int j = 0; j < 8; ++j) {
      const float qv = (float)qf[kk][j];
      ss = fmaf(qv, qv, ss);
    }
  ss += __shfl_xor(ss, 16, 64);
  ss += __shfl_xor(ss, 32, 64);
  // Redistribute: C-layout lane needs m of rows quad*4+reg (we hold row l15).
  float mlog[4];
#pragma unroll
  for (int reg = 0; reg < 4; ++reg)
    mlog[reg] = __shfl(ss, (lane & 48) | (((lane >> 4) << 2) + reg), 64) * LOG2E;

  f32x4 acco[4] = {};
  float lsum[4] = {0.f, 0.f, 0.f, 0.f};

  for (int kt = 0; kt < NSEQ / 64; ++kt) {
    const bf16_t* Kt = Kb + (size_t)kt * 64 * HD;

    // S = Q K^T
    bf16x8 kf[4][2];
#pragma unroll
    for (int nt = 0; nt < 4; ++nt)
#pragma unroll
      for (int kk = 0; kk < 2; ++kk)
        kf[nt][kk] = *(const bf16x8*)(Kt + (size_t)(nt * 16 + l15) * HD +
                                      kk * 32 + quad * 8);
    f32x4 s[4] = {};
#pragma unroll
    for (int nt = 0; nt < 4; ++nt) {
      s[nt] = __builtin_amdgcn_mfma_f32_16x16x32_bf16(qf[0], kf[nt][0], s[nt], 0, 0, 0);
      s[nt] = __builtin_amdgcn_mfma_f32_16x16x32_bf16(qf[1], kf[nt][1], s[nt], 0, 0, 0);
    }

    // P = exp(S - m): no reductions, no rescale. Accumulate row-sum per lane.
#pragma unroll
    for (int nt = 0; nt < 4; ++nt)
#pragma unroll
      for (int reg = 0; reg < 4; ++reg) {
        const float p = __builtin_amdgcn_exp2f(fmaf(s[nt][reg], LOG2E, -mlog[reg]));
        lsum[reg] += p;
        Pl[w][quad * 4 + reg][nt * 16 + l15] = (bf16_t)p;
      }

    // O += P V  (P via LDS C->A relayout; V^T B-frags contiguous from global)
#pragma unroll
    for (int kk = 0; kk < 2; ++kk) {
      bf16x8 vfs[4];
#pragma unroll
      for (int dt = 0; dt < 4; ++dt)
        vfs[dt] = *(const bf16x8*)(Vb + (size_t)(dt * 16 + l15) * NSEQ +
                                   kt * 64 + kk * 32 + quad * 8);
      const bf16x8 pf = *(const bf16x8*)(&Pl[w][l15][kk * 32 + quad * 8]);
#pragma unroll
      for (int dt = 0; dt < 4; ++dt)
        acco[dt] = __builtin_amdgcn_mfma_f32_16x16x32_bf16(pf, vfs[dt], acco[dt], 0, 0, 0);
    }
  }

  // One cross-lane reduction for l (over the 16 l15 lanes of each quad).
#pragma unroll
  for (int off = 1; off <= 8; off <<= 1)
#pragma unroll
    for (int reg = 0; reg < 4; ++reg)
      lsum[reg] += __shfl_xor(lsum[reg], off, 64);

  const float SCL = 0.044194173824159216f;  // 1/sqrt(512)
  float f[4];
#pragma unroll
  for (int reg = 0; reg < 4; ++reg) f[reg] = SCL / lsum[reg];

#pragma unroll
  for (int dt = 0; dt < 4; ++dt) {
    const int d = dt * 16 + l15;
#pragma unroll
    for (int reg = 0; reg < 4; ++reg) {
      const int n = rowbase + quad * 4 + reg;
      out[((size_t)(b * NSEQ + n)) * EMB + h * HD + d] = acco[dt][reg] * f[reg];
    }
  }
}

extern "C" void kernel_launch(void* const* d_in, const int* in_sizes, int n_in,
                              void* d_out, int out_size, void* d_ws, size_t ws_size,
                              hipStream_t stream) {
  const float* x  = (const float*)d_in[0];
  const float* Wk = (const float*)d_in[1];
  const float* bk = (const float*)d_in[2];
  const float* Wv = (const float*)d_in[3];
  const float* bv = (const float*)d_in[4];
  float* out = (float*)d_out;

  bf16_t* Kh  = (bf16_t*)d_ws;                                  // 8 MB
  bf16_t* Vt  = Kh + (size_t)BATCH * HEADS * NSEQ * HD;         // 8 MB
  bf16_t* xb  = Vt + (size_t)BATCH * HEADS * NSEQ * HD;         // 8 MB
  bf16_t* Wkb = xb + (size_t)BATCH * NSEQ * EMB;                // 0.5 MB
  bf16_t* Wvb = Wkb + (size_t)EMB * EMB;                        // 0.5 MB

  convert_kernel<<<1024, 256, 0, stream>>>(x, Wk, Wv, xb, Wkb, Wvb);

  dim3 pg(8192 / 128, EMB / 128, 2);
  proj_kernel<<<pg, 256, 0, stream>>>(xb, Wkb, bk, Wvb, bv, Kh, Vt);

  dim3 fg(BATCH * HEADS, NSEQ / 64);
  flash_kernel<<<fg, 256, 0, stream>>>(Kh, Vt, out);
}

// Round 3
// 147.883 us; speedup vs baseline: 2.1665x; 2.1665x over previous
//
#include <hip/hip_runtime.h>

typedef __bf16 bf16_t;
typedef bf16_t bf16x8 __attribute__((ext_vector_type(8)));
typedef float f32x4 __attribute__((ext_vector_type(4)));

#define NSEQ 2048
#define EMB 512
#define HEADS 8
#define HD 64
#define BATCH 4
#define LOG2E 1.4426950408889634f

#define MFMA16(a, b, c) __builtin_amdgcn_mfma_f32_16x16x32_bf16(a, b, c, 0, 0, 0)

// ---------------------------------------------------------------------------
// fp32 -> bf16 pre-convert: xb (4M el), then Wk||Wv stacked as Wb[1024][512].
// ---------------------------------------------------------------------------
#define CX (BATCH * NSEQ * EMB / 8)
#define CW (EMB * EMB / 8)
__global__ __launch_bounds__(256) void convert_kernel(
    const float* __restrict__ x, const float* __restrict__ Wk,
    const float* __restrict__ Wv,
    bf16_t* __restrict__ xb, bf16_t* __restrict__ Wb)
{
  const int total = CX + 2 * CW;
  for (int c = blockIdx.x * 256 + threadIdx.x; c < total; c += gridDim.x * 256) {
    const float* src;
    bf16_t* dst;
    int off;
    if (c < CX)            { src = x;  dst = xb;      off = c; }
    else if (c < CX + CW)  { src = Wk; dst = Wb;      off = c - CX; }
    else                   { src = Wv; dst = Wb + (size_t)EMB * EMB; off = c - CX - CW; }
    const float4 a = *(const float4*)(src + (size_t)off * 8);
    const float4 bq = *(const float4*)(src + (size_t)off * 8 + 4);
    bf16x8 v;
    v[0] = (bf16_t)a.x;  v[1] = (bf16_t)a.y;  v[2] = (bf16_t)a.z;  v[3] = (bf16_t)a.w;
    v[4] = (bf16_t)bq.x; v[5] = (bf16_t)bq.y; v[6] = (bf16_t)bq.z; v[7] = (bf16_t)bq.w;
    *(bf16x8*)(dst + (size_t)off * 8) = v;
  }
}

// ---------------------------------------------------------------------------
// Fused K/V projection GEMM: C[8192,1024] = xb @ [Wk;Wv]^T + [bk;bv].
// 128x128 tile, BK=64, register-prefetch pipeline, kk-split pitch-40 LDS.
// Epilogue transposes through LDS: Kh[b][h][n][d], Vt[b][h][d][n], coalesced.
// ---------------------------------------------------------------------------
__global__ __launch_bounds__(256, 2) void proj_kernel(
    const bf16_t* __restrict__ xb, const bf16_t* __restrict__ Wb,
    const float* __restrict__ bk, const float* __restrict__ bv,
    bf16_t* __restrict__ Kh, bf16_t* __restrict__ Vt)
{
  __shared__ union {
    struct {
      __align__(16) bf16_t A[2][128][40];   // [kk-half][row][32 el + pad]
      __align__(16) bf16_t B[2][128][40];
    } s;
    __align__(16) bf16_t T[128][136];       // epilogue transpose buffer
  } u;

  const int t    = threadIdx.x;
  const int w    = t >> 6;
  const int lane = t & 63;
  const int quad = lane >> 4;
  const int l15  = lane & 15;
  const int wr   = w >> 1, wc = w & 1;
  const int m0   = blockIdx.x * 128;
  const int n0   = blockIdx.y * 128;        // stacked feature base 0..896
  const int zz   = (blockIdx.y >= 4);       // 0: K-features, 1: V-features

  const int sr = t >> 3;        // staging row 0..31 (x4 groups)
  const int sj = t & 7;         // 16B chunk 0..7 within 64-el k slab
  const int sb = sj >> 2, sc = (sj & 3) * 8;

  bf16x8 pa[4], pb[4];
  auto prefetch = [&](int k0) {
#pragma unroll
    for (int i = 0; i < 4; ++i) {
      pa[i] = *(const bf16x8*)(xb + (size_t)(m0 + sr + i * 32) * EMB + k0 + sj * 8);
      pb[i] = *(const bf16x8*)(Wb + (size_t)(n0 + sr + i * 32) * EMB + k0 + sj * 8);
    }
  };

  f32x4 acc[4][4] = {};
  prefetch(0);

  for (int it = 0; it < 8; ++it) {
    __syncthreads();
#pragma unroll
    for (int i = 0; i < 4; ++i) {
      *(bf16x8*)(&u.s.A[sb][sr + i * 32][sc]) = pa[i];
      *(bf16x8*)(&u.s.B[sb][sr + i * 32][sc]) = pb[i];
    }
    __syncthreads();
    if (it < 7) prefetch((it + 1) * 64);

    bf16x8 af[4][2], bf[4][2];
#pragma unroll
    for (int mt = 0; mt < 4; ++mt)
#pragma unroll
      for (int kk = 0; kk < 2; ++kk)
        af[mt][kk] = *(const bf16x8*)(&u.s.A[kk][wr * 64 + mt * 16 + l15][quad * 8]);
#pragma unroll
    for (int nt = 0; nt < 4; ++nt)
#pragma unroll
      for (int kk = 0; kk < 2; ++kk)
        bf[nt][kk] = *(const bf16x8*)(&u.s.B[kk][wc * 64 + nt * 16 + l15][quad * 8]);
#pragma unroll
    for (int kk = 0; kk < 2; ++kk)
#pragma unroll
      for (int mt = 0; mt < 4; ++mt)
#pragma unroll
        for (int nt = 0; nt < 4; ++nt)
          acc[mt][nt] = MFMA16(af[mt][kk], bf[nt][kk], acc[mt][nt]);
  }

  __syncthreads();  // staging LDS -> transpose buffer reuse

  // Stage 1: +bias, bf16, into LDS in output-major layout.
#pragma unroll
  for (int mt = 0; mt < 4; ++mt) {
#pragma unroll
    for (int nt = 0; nt < 4; ++nt) {
      const int F = wc * 64 + nt * 16 + l15;       // local feature 0..127
      const int c = n0 + F;                        // stacked feature 0..1023
      const float bb = zz ? bv[c - 512] : bk[c];
#pragma unroll
      for (int reg = 0; reg < 4; ++reg) {
        const int R = wr * 64 + mt * 16 + quad * 4 + reg;  // local row 0..127
        const float v = acc[mt][nt][reg] + bb;
        if (!zz) u.T[R][F] = (bf16_t)v;   // Kh: [n][feat]
        else     u.T[F][R] = (bf16_t)v;   // Vt: [feat][n]
      }
    }
  }
  __syncthreads();

  // Stage 2: coalesced bf16x8 stores.
#pragma unroll
  for (int i = 0; i < 8; ++i) {
    const int q  = t + i * 256;       // 0..2047
    const int R  = q >> 4;            // LDS row 0..127
    const int C8 = (q & 15) * 8;      // LDS col chunk
    const bf16x8 v = *(const bf16x8*)(&u.T[R][C8]);
    if (!zz) {
      const int gr = m0 + R, b = gr >> 11, n = gr & (NSEQ - 1);
      const int c = n0 + C8, hh = c >> 6, d = c & 63;
      *(bf16x8*)(Kh + (((size_t)(b * HEADS + hh)) * NSEQ + n) * HD + d) = v;
    } else {
      const int cv = n0 + R - 512, hh = cv >> 6, d = cv & 63;
      const int gr = m0 + C8, b = gr >> 11, n = gr & (NSEQ - 1);
      *(bf16x8*)(Vt + (((size_t)(b * HEADS + hh)) * HD + d) * NSEQ + n) = v;
    }
  }
}

// ---------------------------------------------------------------------------
// Flash attention, Q = K, fixed row max m_i = ||k_i||^2 (validated R2).
// Block = 4 waves x 32 Q-rows = 128 rows. K/V tiles (64 keys) staged in LDS
// with COALESCED global loads + register prefetch pipeline; frags read from
// kk-split pitch-40 LDS (2-way free). P via per-wave pitch-68 LDS (0-conflict
// in R2). Grid (32 bh, 16 mtile); id%8 = bh%8 -> 4 heads/XCD, K/V fit L2.
// ---------------------------------------------------------------------------
__global__ __launch_bounds__(256, 2) void flash_kernel(
    const bf16_t* __restrict__ Kh, const bf16_t* __restrict__ Vt,
    float* __restrict__ out)
{
  __shared__ __align__(16) bf16_t Kl[2][64][40];   // [kk][key][32 el + pad]
  __shared__ __align__(16) bf16_t Vl[2][64][40];   // [kk][d][32 keys + pad]
  __shared__ __align__(16) bf16_t Pl[4][32][68];   // per-wave P relayout

  const int t    = threadIdx.x;
  const int w    = t >> 6;
  const int lane = t & 63;
  const int quad = lane >> 4;
  const int l15  = lane & 15;

  const int bh = blockIdx.x;           // 0..31
  const int b  = bh >> 3, h = bh & 7;
  const int rowbase = blockIdx.y * 128 + w * 32;

  const bf16_t* __restrict__ Kb = Kh + (size_t)bh * NSEQ * HD;
  const bf16_t* __restrict__ Vb = Vt + (size_t)bh * HD * NSEQ;

  // Resident Q fragments (one-time uncoalesced cost).
  bf16x8 qf[2][2];
#pragma unroll
  for (int mt = 0; mt < 2; ++mt)
#pragma unroll
    for (int kk = 0; kk < 2; ++kk)
      qf[mt][kk] = *(const bf16x8*)(Kb + (size_t)(rowbase + mt * 16 + l15) * HD +
                                    kk * 32 + quad * 8);

  // Fixed max: m_i = ||k_i||^2, from resident frags; 2 shuffles + redistribute.
  float mlog[2][4];
#pragma unroll
  for (int mt = 0; mt < 2; ++mt) {
    float ss = 0.f;
#pragma unroll
    for (int kk = 0; kk < 2; ++kk)
#pragma unroll
      for (int j = 0; j < 8; ++j) {
        const float qv = (float)qf[mt][kk][j];
        ss = fmaf(qv, qv, ss);
      }
    ss += __shfl_xor(ss, 16, 64);
    ss += __shfl_xor(ss, 32, 64);
#pragma unroll
    for (int reg = 0; reg < 4; ++reg)
      mlog[mt][reg] =
          __shfl(ss, (lane & 48) | (((lane >> 4) << 2) + reg), 64) * LOG2E;
  }

  // Staging indices: thread t handles 16B chunk sj of row sr (and sr+32).
  const int sr = t >> 3, sj = t & 7;
  const int sb = sj >> 2, sc = (sj & 3) * 8;

  bf16x8 pk[2], pv[2];
  auto prefetch = [&](int kt) {
    const bf16_t* Kt = Kb + (size_t)kt * 64 * HD;   // contiguous 8 KB
    pk[0] = *(const bf16x8*)(Kt + (size_t)sr * HD + sj * 8);
    pk[1] = *(const bf16x8*)(Kt + (size_t)(sr + 32) * HD + sj * 8);
    pv[0] = *(const bf16x8*)(Vb + (size_t)sr * NSEQ + kt * 64 + sj * 8);
    pv[1] = *(const bf16x8*)(Vb + (size_t)(sr + 32) * NSEQ + kt * 64 + sj * 8);
  };

  f32x4 acco[2][4] = {};
  float lsum[2][4] = {};

  prefetch(0);

  for (int kt = 0; kt < NSEQ / 64; ++kt) {
    __syncthreads();
    *(bf16x8*)(&Kl[sb][sr][sc])      = pk[0];
    *(bf16x8*)(&Kl[sb][sr + 32][sc]) = pk[1];
    *(bf16x8*)(&Vl[sb][sr][sc])      = pv[0];
    *(bf16x8*)(&Vl[sb][sr + 32][sc]) = pv[1];
    __syncthreads();
    if (kt + 1 < NSEQ / 64) prefetch(kt + 1);

    // S = Q K^T from LDS frags.
    bf16x8 kf[4][2];
#pragma unroll
    for (int nt = 0; nt < 4; ++nt)
#pragma unroll
      for (int kk = 0; kk < 2; ++kk)
        kf[nt][kk] = *(const bf16x8*)(&Kl[kk][nt * 16 + l15][quad * 8]);

    f32x4 s[2][4] = {};
#pragma unroll
    for (int mt = 0; mt < 2; ++mt)
#pragma unroll
      for (int nt = 0; nt < 4; ++nt) {
        s[mt][nt] = MFMA16(qf[mt][0], kf[nt][0], s[mt][nt]);
        s[mt][nt] = MFMA16(qf[mt][1], kf[nt][1], s[mt][nt]);
      }

    // P = exp(S - m); per-lane row-sum; scatter P to per-wave LDS.
#pragma unroll
    for (int mt = 0; mt < 2; ++mt)
#pragma unroll
      for (int nt = 0; nt < 4; ++nt)
#pragma unroll
        for (int reg = 0; reg < 4; ++reg) {
          const float p =
              __builtin_amdgcn_exp2f(fmaf(s[mt][nt][reg], LOG2E, -mlog[mt][reg]));
          lsum[mt][reg] += p;
          Pl[w][mt * 16 + quad * 4 + reg][nt * 16 + l15] = (bf16_t)p;
        }

    // O += P V from LDS frags.
#pragma unroll
    for (int kk = 0; kk < 2; ++kk) {
      bf16x8 vfs[4];
#pragma unroll
      for (int dt = 0; dt < 4; ++dt)
        vfs[dt] = *(const bf16x8*)(&Vl[kk][dt * 16 + l15][quad * 8]);
#pragma unroll
      for (int mt = 0; mt < 2; ++mt) {
        const bf16x8 pf =
            *(const bf16x8*)(&Pl[w][mt * 16 + l15][kk * 32 + quad * 8]);
#pragma unroll
        for (int dt = 0; dt < 4; ++dt)
          acco[mt][dt] = MFMA16(pf, vfs[dt], acco[mt][dt]);
      }
    }
  }

  // Final l reduction (over l15 lanes) and scaled output.
#pragma unroll
  for (int mt = 0; mt < 2; ++mt)
#pragma unroll
    for (int off = 1; off <= 8; off <<= 1)
#pragma unroll
      for (int reg = 0; reg < 4; ++reg)
        lsum[mt][reg] += __shfl_xor(lsum[mt][reg], off, 64);

  const float SCL = 0.044194173824159216f;  // 1/sqrt(512)
#pragma unroll
  for (int mt = 0; mt < 2; ++mt)
#pragma unroll
    for (int dt = 0; dt < 4; ++dt) {
      const int d = dt * 16 + l15;
#pragma unroll
      for (int reg = 0; reg < 4; ++reg) {
        const int n = rowbase + mt * 16 + quad * 4 + reg;
        const float f = SCL / lsum[mt][reg];
        out[((size_t)(b * NSEQ + n)) * EMB + h * HD + d] = acco[mt][dt][reg] * f;
      }
    }
}

extern "C" void kernel_launch(void* const* d_in, const int* in_sizes, int n_in,
                              void* d_out, int out_size, void* d_ws, size_t ws_size,
                              hipStream_t stream) {
  const float* x  = (const float*)d_in[0];
  const float* Wk = (const float*)d_in[1];
  const float* bk = (const float*)d_in[2];
  const float* Wv = (const float*)d_in[3];
  const float* bv = (const float*)d_in[4];
  float* out = (float*)d_out;

  bf16_t* Kh = (bf16_t*)d_ws;                                   // 8 MB
  bf16_t* Vt = Kh + (size_t)BATCH * HEADS * NSEQ * HD;          // 8 MB
  bf16_t* xb = Vt + (size_t)BATCH * HEADS * NSEQ * HD;          // 8 MB
  bf16_t* Wb = xb + (size_t)BATCH * NSEQ * EMB;                 // 1 MB stacked

  convert_kernel<<<1024, 256, 0, stream>>>(x, Wk, Wv, xb, Wb);

  dim3 pg(8192 / 128, 1024 / 128);
  proj_kernel<<<pg, 256, 0, stream>>>(xb, Wb, bk, bv, Kh, Vt);

  dim3 fg(BATCH * HEADS, NSEQ / 128);
  flash_kernel<<<fg, 256, 0, stream>>>(Kh, Vt, out);
}

// Round 4
// 133.609 us; speedup vs baseline: 2.3979x; 1.1068x over previous
//
#include <hip/hip_runtime.h>

typedef __bf16 bf16_t;
typedef bf16_t bf16x8 __attribute__((ext_vector_type(8)));
typedef float f32x4 __attribute__((ext_vector_type(4)));

#define NSEQ 2048
#define EMB 512
#define HEADS 8
#define HD 64
#define BATCH 4
#define LOG2E 1.4426950408889634f

#define MFMA16(a, b, c) __builtin_amdgcn_mfma_f32_16x16x32_bf16(a, b, c, 0, 0, 0)

// ---------------------------------------------------------------------------
// Fused K/V projection GEMM with INLINE fp32->bf16 convert (no separate
// convert kernel): C[8192,1024] = x @ [Wk;Wv]^T + [bk;bv].
// 128x128 tile, BK=64, register-prefetch pipeline, kk-split pitch-40 LDS.
// Epilogue transposes through LDS: Kh[b][h][n][d], Vt[b][h][d][n], coalesced.
// ---------------------------------------------------------------------------
__global__ __launch_bounds__(256, 2) void proj_kernel(
    const float* __restrict__ x,
    const float* __restrict__ Wk, const float* __restrict__ bk,
    const float* __restrict__ Wv, const float* __restrict__ bv,
    bf16_t* __restrict__ Kh, bf16_t* __restrict__ Vt)
{
  __shared__ union {
    struct {
      __align__(16) bf16_t A[2][128][40];   // [kk-half][row][32 el + pad]
      __align__(16) bf16_t B[2][128][40];
    } s;
    __align__(16) bf16_t T[128][136];       // epilogue transpose buffer
  } u;

  const int t    = threadIdx.x;
  const int w    = t >> 6;
  const int lane = t & 63;
  const int quad = lane >> 4;
  const int l15  = lane & 15;
  const int wr   = w >> 1, wc = w & 1;
  const int m0   = blockIdx.x * 128;
  const int n0   = blockIdx.y * 128;        // stacked feature base 0..896
  const int zz   = (blockIdx.y >= 4);       // 0: K-features, 1: V-features
  const float* __restrict__ W = zz ? Wv : Wk;
  const int nW = n0 - zz * 512;             // row base within W

  const int sr = t >> 3;        // staging row 0..31 (x4 groups)
  const int sj = t & 7;         // 8-el chunk 0..7 within 64-el k slab
  const int sb = sj >> 2, sc = (sj & 3) * 8;

  float4 pa[4][2], pb[4][2];
  auto prefetch = [&](int k0) {
#pragma unroll
    for (int i = 0; i < 4; ++i) {
      const float* xa = x + (size_t)(m0 + sr + i * 32) * EMB + k0 + sj * 8;
      const float* wa = W + (size_t)(nW + sr + i * 32) * EMB + k0 + sj * 8;
      pa[i][0] = *(const float4*)xa; pa[i][1] = *(const float4*)(xa + 4);
      pb[i][0] = *(const float4*)wa; pb[i][1] = *(const float4*)(wa + 4);
    }
  };
  auto pack8 = [](float4 a, float4 b) -> bf16x8 {
    bf16x8 v;
    v[0] = (bf16_t)a.x; v[1] = (bf16_t)a.y; v[2] = (bf16_t)a.z; v[3] = (bf16_t)a.w;
    v[4] = (bf16_t)b.x; v[5] = (bf16_t)b.y; v[6] = (bf16_t)b.z; v[7] = (bf16_t)b.w;
    return v;
  };

  f32x4 acc[4][4] = {};
  prefetch(0);

  for (int it = 0; it < 8; ++it) {
    __syncthreads();
#pragma unroll
    for (int i = 0; i < 4; ++i) {
      *(bf16x8*)(&u.s.A[sb][sr + i * 32][sc]) = pack8(pa[i][0], pa[i][1]);
      *(bf16x8*)(&u.s.B[sb][sr + i * 32][sc]) = pack8(pb[i][0], pb[i][1]);
    }
    __syncthreads();
    if (it < 7) prefetch((it + 1) * 64);

    bf16x8 af[4][2], bf[4][2];
#pragma unroll
    for (int mt = 0; mt < 4; ++mt)
#pragma unroll
      for (int kk = 0; kk < 2; ++kk)
        af[mt][kk] = *(const bf16x8*)(&u.s.A[kk][wr * 64 + mt * 16 + l15][quad * 8]);
#pragma unroll
    for (int nt = 0; nt < 4; ++nt)
#pragma unroll
      for (int kk = 0; kk < 2; ++kk)
        bf[nt][kk] = *(const bf16x8*)(&u.s.B[kk][wc * 64 + nt * 16 + l15][quad * 8]);
#pragma unroll
    for (int kk = 0; kk < 2; ++kk)
#pragma unroll
      for (int mt = 0; mt < 4; ++mt)
#pragma unroll
        for (int nt = 0; nt < 4; ++nt)
          acc[mt][nt] = MFMA16(af[mt][kk], bf[nt][kk], acc[mt][nt]);
  }

  __syncthreads();  // staging LDS -> transpose buffer reuse

  // Stage 1: +bias, bf16, into LDS in output-major layout.
#pragma unroll
  for (int mt = 0; mt < 4; ++mt) {
#pragma unroll
    for (int nt = 0; nt < 4; ++nt) {
      const int F = wc * 64 + nt * 16 + l15;       // local feature 0..127
      const int c = n0 + F;                        // stacked feature 0..1023
      const float bb = zz ? bv[c - 512] : bk[c];
#pragma unroll
      for (int reg = 0; reg < 4; ++reg) {
        const int R = wr * 64 + mt * 16 + quad * 4 + reg;  // local row 0..127
        const float v = acc[mt][nt][reg] + bb;
        if (!zz) u.T[R][F] = (bf16_t)v;   // Kh: [n][feat]
        else     u.T[F][R] = (bf16_t)v;   // Vt: [feat][n]
      }
    }
  }
  __syncthreads();

  // Stage 2: coalesced bf16x8 stores.
#pragma unroll
  for (int i = 0; i < 8; ++i) {
    const int q  = t + i * 256;       // 0..2047
    const int R  = q >> 4;            // LDS row 0..127
    const int C8 = (q & 15) * 8;      // LDS col chunk
    const bf16x8 v = *(const bf16x8*)(&u.T[R][C8]);
    if (!zz) {
      const int gr = m0 + R, b = gr >> 11, n = gr & (NSEQ - 1);
      const int c = n0 + C8, hh = c >> 6, d = c & 63;
      *(bf16x8*)(Kh + (((size_t)(b * HEADS + hh)) * NSEQ + n) * HD + d) = v;
    } else {
      const int cv = n0 + R - 512, hh = cv >> 6, d = cv & 63;
      const int gr = m0 + C8, b = gr >> 11, n = gr & (NSEQ - 1);
      *(bf16x8*)(Vt + (((size_t)(b * HEADS + hh)) * HD + d) * NSEQ + n) = v;
    }
  }
}

// ---------------------------------------------------------------------------
// Flash attention, Q = K, fixed row max m_i = ||k_i||^2 (validated R2/R3).
// S computed TRANSPOSED (S^T = K.Q^T; Q's A-frag doubles as Q^T's B-frag):
//   - C-layout col = q-row -> mlog needs no redistribution
//   - lane's 4 regs = 4 consecutive keys -> P stores are b64, not b16
// Wave = 64 q-rows x 32 keys; 4 waves split 2x2 over (row-half, key-half).
// Block = 128 rows x 64-key rounds; split-K partials combined via LDS at end
// (fixed max => partials just add). Grid (32 bh, 16) = 512 blocks, 2/CU.
// ---------------------------------------------------------------------------
__global__ __launch_bounds__(256, 2) void flash_kernel(
    const bf16_t* __restrict__ Kh, const bf16_t* __restrict__ Vt,
    float* __restrict__ out)
{
  __shared__ union {
    struct {
      __align__(16) bf16_t Kl[2][64][40];   // [d-half][key][32 el + pad]
      __align__(16) bf16_t Vl[2][64][40];   // [key-half][d][32 keys + pad]
      __align__(16) bf16_t Pl[4][64][40];   // per-wave P [qrow][32 keys + pad]
    } s;
    struct {
      __align__(16) float Cb[2][4096];      // key-half-1 O partials (flat)
      __align__(16) float Lb[2][64][4];     // key-half-1 l partials
    } c;
  } u;

  const int t    = threadIdx.x;
  const int w    = t >> 6;
  const int lane = t & 63;
  const int quad = lane >> 4;
  const int l15  = lane & 15;
  const int rh   = w & 1;              // row-half
  const int kh   = w >> 1;             // key-half

  const int bh = blockIdx.x;           // 0..31 (id%8 = bh%8 -> XCD locality)
  const int b  = bh >> 3, h = bh & 7;
  const int rowbase = blockIdx.y * 128 + rh * 64;

  const bf16_t* __restrict__ Kb = Kh + (size_t)bh * NSEQ * HD;
  const bf16_t* __restrict__ Vb = Vt + (size_t)bh * HD * NSEQ;

  // Resident Q fragments: qf[nt] = A-frag of Q rows (== B-frag of Q^T).
  bf16x8 qf[4][2];
#pragma unroll
  for (int nt = 0; nt < 4; ++nt)
#pragma unroll
    for (int kk = 0; kk < 2; ++kk)
      qf[nt][kk] = *(const bf16x8*)(Kb + (size_t)(rowbase + nt * 16 + l15) * HD +
                                    kk * 32 + quad * 8);

  // Fixed max m_i = ||k_i||^2; lane's q-row for tile nt is nt*16+l15.
  float mlog[4];
#pragma unroll
  for (int nt = 0; nt < 4; ++nt) {
    float ss = 0.f;
#pragma unroll
    for (int kk = 0; kk < 2; ++kk)
#pragma unroll
      for (int j = 0; j < 8; ++j) {
        const float qv = (float)qf[nt][kk][j];
        ss = fmaf(qv, qv, ss);
      }
    ss += __shfl_xor(ss, 16, 64);
    ss += __shfl_xor(ss, 32, 64);
    mlog[nt] = ss * LOG2E;
  }

  // Staging: thread t covers rows sr, sr+32 (16B chunk sj).
  const int sr = t >> 3, sj = t & 7;
  const int sb = sj >> 2, sc = (sj & 3) * 8;

  bf16x8 pk[2], pv[2];
  auto prefetch = [&](int kt) {
    const bf16_t* Kt = Kb + (size_t)kt * 64 * HD;   // contiguous 8 KB
    pk[0] = *(const bf16x8*)(Kt + (size_t)sr * HD + sj * 8);
    pk[1] = *(const bf16x8*)(Kt + (size_t)(sr + 32) * HD + sj * 8);
    pv[0] = *(const bf16x8*)(Vb + (size_t)sr * NSEQ + kt * 64 + sj * 8);
    pv[1] = *(const bf16x8*)(Vb + (size_t)(sr + 32) * NSEQ + kt * 64 + sj * 8);
  };

  f32x4 acco[4][4] = {};                 // [row-tile][d-tile]
  float lsum[4] = {0.f, 0.f, 0.f, 0.f};  // per q-row-tile, partial over lanes

  prefetch(0);

  for (int kt = 0; kt < NSEQ / 64; ++kt) {
    __syncthreads();
    *(bf16x8*)(&u.s.Kl[sb][sr][sc])      = pk[0];
    *(bf16x8*)(&u.s.Kl[sb][sr + 32][sc]) = pk[1];
    *(bf16x8*)(&u.s.Vl[sb][sr][sc])      = pv[0];
    *(bf16x8*)(&u.s.Vl[sb][sr + 32][sc]) = pv[1];
    __syncthreads();
    if (kt + 1 < NSEQ / 64) prefetch(kt + 1);

    // S^T = K . Q^T over this wave's 32-key half.
    bf16x8 kf[2][2];
#pragma unroll
    for (int jt = 0; jt < 2; ++jt)
#pragma unroll
      for (int kk = 0; kk < 2; ++kk)
        kf[jt][kk] =
            *(const bf16x8*)(&u.s.Kl[kk][kh * 32 + jt * 16 + l15][quad * 8]);

    f32x4 st[2][4] = {};
#pragma unroll
    for (int kk = 0; kk < 2; ++kk)
#pragma unroll
      for (int jt = 0; jt < 2; ++jt)
#pragma unroll
        for (int nt = 0; nt < 4; ++nt)
          st[jt][nt] = MFMA16(kf[jt][kk], qf[nt][kk], st[jt][nt]);

    // P = exp(S - m); lane: q-row nt*16+l15, keys jt*16+quad*4+reg -> b64.
#pragma unroll
    for (int jt = 0; jt < 2; ++jt)
#pragma unroll
      for (int nt = 0; nt < 4; ++nt) {
        union { bf16_t hx[4]; uint2 u2; } pw;
#pragma unroll
        for (int reg = 0; reg < 4; ++reg) {
          const float p =
              __builtin_amdgcn_exp2f(fmaf(st[jt][nt][reg], LOG2E, -mlog[nt]));
          lsum[nt] += p;
          pw.hx[reg] = (bf16_t)p;
        }
        *(uint2*)(&u.s.Pl[w][nt * 16 + l15][jt * 16 + quad * 4]) = pw.u2;
      }

    // O += P V over the 32-key half (K-dim = 32 = one MFMA step).
    bf16x8 vf[4];
#pragma unroll
    for (int dt = 0; dt < 4; ++dt)
      vf[dt] = *(const bf16x8*)(&u.s.Vl[kh][dt * 16 + l15][quad * 8]);
#pragma unroll
    for (int rt = 0; rt < 4; ++rt) {
      const bf16x8 pf = *(const bf16x8*)(&u.s.Pl[w][rt * 16 + l15][quad * 8]);
#pragma unroll
      for (int dt = 0; dt < 4; ++dt)
        acco[rt][dt] = MFMA16(pf, vf[dt], acco[rt][dt]);
    }
  }

  // Split-K combine: key-half-1 waves dump partials; key-half-0 waves add.
  __syncthreads();
  if (kh == 1) {
#pragma unroll
    for (int rt = 0; rt < 4; ++rt)
#pragma unroll
      for (int dt = 0; dt < 4; ++dt)
        *(f32x4*)(&u.c.Cb[rh][((rt * 4 + dt) * 64 + lane) * 4]) = acco[rt][dt];
#pragma unroll
    for (int nt = 0; nt < 4; ++nt) u.c.Lb[rh][lane][nt] = lsum[nt];
  }
  __syncthreads();
  if (kh == 0) {
#pragma unroll
    for (int rt = 0; rt < 4; ++rt)
#pragma unroll
      for (int dt = 0; dt < 4; ++dt) {
        const f32x4 o = *(const f32x4*)(&u.c.Cb[rh][((rt * 4 + dt) * 64 + lane) * 4]);
        acco[rt][dt] += o;
      }
#pragma unroll
    for (int nt = 0; nt < 4; ++nt) {
      lsum[nt] += u.c.Lb[rh][lane][nt];
      lsum[nt] += __shfl_xor(lsum[nt], 16, 64);
      lsum[nt] += __shfl_xor(lsum[nt], 32, 64);
    }

    const float SCL = 0.044194173824159216f;  // 1/sqrt(512)
#pragma unroll
    for (int rt = 0; rt < 4; ++rt)
#pragma unroll
      for (int reg = 0; reg < 4; ++reg) {
        // O C-layout row = rt*16+quad*4+reg; its l lives at lane l15=quad*4+reg.
        const float lr = __shfl(lsum[rt], quad * 4 + reg, 64);
        const float f = SCL / lr;
        const int n = rowbase + rt * 16 + quad * 4 + reg;
#pragma unroll
        for (int dt = 0; dt < 4; ++dt)
          out[((size_t)(b * NSEQ + n)) * EMB + h * HD + dt * 16 + l15] =
              acco[rt][dt][reg] * f;
      }
  }
}

extern "C" void kernel_launch(void* const* d_in, const int* in_sizes, int n_in,
                              void* d_out, int out_size, void* d_ws, size_t ws_size,
                              hipStream_t stream) {
  const float* x  = (const float*)d_in[0];
  const float* Wk = (const float*)d_in[1];
  const float* bk = (const float*)d_in[2];
  const float* Wv = (const float*)d_in[3];
  const float* bv = (const float*)d_in[4];
  float* out = (float*)d_out;

  bf16_t* Kh = (bf16_t*)d_ws;                                   // 8 MB
  bf16_t* Vt = Kh + (size_t)BATCH * HEADS * NSEQ * HD;          // 8 MB

  dim3 pg(8192 / 128, 1024 / 128);
  proj_kernel<<<pg, 256, 0, stream>>>(x, Wk, bk, Wv, bv, Kh, Vt);

  dim3 fg(BATCH * HEADS, NSEQ / 128);
  flash_kernel<<<fg, 256, 0, stream>>>(Kh, Vt, out);
}